// Round 6
// baseline (3362.781 us; speedup 1.0000x reference)
//
#include <hip/hip_runtime.h>
#include <hip/hip_cooperative_groups.h>

namespace cg = cooperative_groups;

#define Dd 1024
#define Bb 128
#define Tt 256
#define NWG 256
#define NTHR 256

typedef short bf16x8 __attribute__((ext_vector_type(8)));
typedef float f32x4 __attribute__((ext_vector_type(4)));
typedef unsigned int u32x4 __attribute__((ext_vector_type(4)));
typedef unsigned long long u64;

static __device__ __forceinline__ unsigned short f2bf(float x) {
  unsigned int u = __float_as_uint(x);
  u += 0x7fffu + ((u >> 16) & 1u);   // round-to-nearest-even
  return (unsigned short)(u >> 16);
}
static __device__ __forceinline__ unsigned int pk2(float a, float b) {
  return (unsigned int)f2bf(a) | ((unsigned int)f2bf(b) << 16);
}
static __device__ __forceinline__ bf16x8 as_bf(uint4 u) {
  union { uint4 u; bf16x8 v; } x; x.u = u; return x.v;
}
static __device__ __forceinline__ f32x4 mfma_(bf16x8 a, bf16x8 b, f32x4 c) {
  return __builtin_amdgcn_mfma_f32_16x16x32_bf16(a, b, c, 0, 0, 0);
}
static __device__ __forceinline__ float sigm(float x) { return 1.f / (1.f + __expf(-x)); }
static __device__ __forceinline__ float tanh_s(float x) { return 1.f - 2.f / (__expf(2.f * x) + 1.f); }
static __device__ __forceinline__ u64 aload(const u64* p) {
  return __hip_atomic_load(p, __ATOMIC_RELAXED, __HIP_MEMORY_SCOPE_AGENT);
}

// 256 WGs x 256 thr. WG = (batch-half bh, hidden-slice gs of 8 dims).
// LDS: W_ih+W_hh slices packed as MFMA B-fragments (128 KB, resident).
// Scan loop: no syncthreads, no cache fences. Flag wait pipelined under the
// x-GEMM; h-read sweep rotated per-WG to spread coherent-point contention;
// publish = one dwordx4 sc0 sc1 store per lane.
__global__ void __launch_bounds__(NTHR, 1) lstm_kernel(
    const float* __restrict__ inp, const float* __restrict__ h0,
    const float* __restrict__ c0, const float* __restrict__ W_ih,
    const float* __restrict__ W_hh, const float* __restrict__ b_ih,
    const float* __restrict__ b_hh, const float* __restrict__ fc_w,
    const float* __restrict__ fc_b, float* __restrict__ out,
    int* __restrict__ flags, unsigned short* __restrict__ hbuf,
    unsigned short* __restrict__ xbf, int use_xbf)
{
  extern __shared__ uint4 ldsW[];   // 8192 fragments = 128 KB
  __shared__ float red[4];

  const int tid = threadIdx.x;
  const int wg  = blockIdx.x;
  const int gid = wg * NTHR + tid;
  cg::grid_group grid = cg::this_grid();

  const int gs = wg >> 1;
  const int bh = wg & 1;

  // ---------- flag init: 4 per WG (one per wave), layout [bh][gs][wave]
  if (tid < 4)
    __hip_atomic_store(&flags[bh * 512 + gs * 4 + tid], 0,
                       __ATOMIC_RELAXED, __HIP_MEMORY_SCOPE_AGENT);

  // ---------- Phase A: inp [B,T,D] f32 -> xbf [T,B,D] bf16 ; h0 -> hbuf[0]
  if (use_xbf) {
    for (int i = gid; i < Tt * Bb * (Dd / 8); i += NWG * NTHR) {
      int d8 = i & 127, b = (i >> 7) & 127, t = i >> 14;
      const float* s = inp + ((size_t)b * Tt + t) * Dd + d8 * 8;
      uint4 p;
      p.x = pk2(s[0], s[1]); p.y = pk2(s[2], s[3]);
      p.z = pk2(s[4], s[5]); p.w = pk2(s[6], s[7]);
      *(uint4*)(xbf + (size_t)i * 8) = p;
    }
  }
  // h0 [b][d] f32 -> hbuf buf0 [d>>3][b][d&7] bf16
  uint4* hb4w = (uint4*)hbuf;
  for (int i = gid; i < 128 * 128; i += NWG * NTHR) {
    int row = i & 127, gsl = i >> 7;
    const float* s = h0 + (size_t)row * Dd + gsl * 8;
    uint4 p;
    p.x = pk2(s[0], s[1]); p.y = pk2(s[2], s[3]);
    p.z = pk2(s[4], s[5]); p.w = pk2(s[6], s[7]);
    hb4w[gsl * 128 + row] = p;
  }

  // ---------- Phase B: pack W slices into LDS (bf16, fragment order)
  for (int i = tid; i < 8192; i += NTHR) {
    int l2 = i & 63, mmct = (i >> 6) & 3, kc = i >> 8;
    int cc = l2 & 15, ct = mmct & 1;
    int row = (((ct << 1) | (cc >> 3)) << 10) | (gs << 3) | (cc & 7);
    int k = kc * 32 + ((l2 >> 4) << 3);
    const float* s = ((mmct & 2) ? W_hh : W_ih) + (size_t)row * Dd + k;
    uint4 p;
    p.x = pk2(s[0], s[1]); p.y = pk2(s[2], s[3]);
    p.z = pk2(s[4], s[5]); p.w = pk2(s[6], s[7]);
    ldsW[i] = p;
  }

  // ---------- per-thread setup
  const int w = tid >> 6, l = tid & 63;
  const int c = l & 15;
  const int rowbase = bh * 64 + w * 16;
  const int arow = rowbase + c;                 // A-fragment batch row
  const int koff8 = l >> 4;                     // k sub-chunk (0..3) within 32
  const int r0 = ((c >> 3) << 10) | (gs << 3) | (c & 7);        // i/f row
  const int r1 = ((2 + (c >> 3)) << 10) | (gs << 3) | (c & 7);  // g/o row
  const float bias0 = b_ih[r0] + b_hh[r0];
  const float bias1 = b_ih[r1] + b_hh[r1];
  const int dim = (gs << 3) | (c & 7);
  const int crow = rowbase + (koff8 << 2);      // C/D fragment row base
  float creg[4];
  #pragma unroll
  for (int j = 0; j < 4; ++j) creg[j] = c0[(size_t)(crow + j) * Dd + dim];

  float* out_y = out;
  float* out_h = out + Bb;
  float* out_c = out + Bb + (size_t)Bb * Dd;

  const u64* hQ = (const u64*)hbuf;   // [buf 32768][kslice 128][row 128][2 u64]
  int* myflag = &flags[bh * 512 + gs * 4 + w];
  const u64* fq = (const u64*)(flags + bh * 512);  // 256 u64 = this half
  const int shbase = ((l & 15) >> 2) * 16;         // shfl source base
  const int rot = gs & 15;                         // h-read sweep rotation

  grid.sync();   // one-time: publish flags reset, xbf, hbuf(0)

  // ---------- sequential scan (no syncthreads, no fences)
  for (int t = 0; t < Tt; ++t) {
    const int cur = t & 1;

    // ---- issue flag loads FIRST; they resolve under the x-GEMM
    u64 fc0 = aload(&fq[l]);
    u64 fc1 = aload(&fq[l + 64]);
    u64 fc2 = aload(&fq[l + 128]);
    u64 fc3 = aload(&fq[l + 192]);

    // ---- x-part: no dependency on h(t)
    f32x4 xa0 = {bias0, bias0, bias0, bias0};
    f32x4 xa1 = {bias1, bias1, bias1, bias1};
    f32x4 xb0 = {0.f, 0.f, 0.f, 0.f};
    f32x4 xb1 = {0.f, 0.f, 0.f, 0.f};

    if (use_xbf) {
      const uint4* xA = (const uint4*)(xbf + ((size_t)t * Bb + arow) * Dd + koff8 * 8);
      #pragma unroll
      for (int kc = 0; kc < 32; kc += 2) {
        uint4 ax0 = xA[kc * 4];
        uint4 ax1 = xA[(kc + 1) * 4];
        const int lb0 = kc * 256 + l, lb1 = (kc + 1) * 256 + l;
        xa0 = mfma_(as_bf(ax0), as_bf(ldsW[lb0]),      xa0);
        xa1 = mfma_(as_bf(ax0), as_bf(ldsW[lb0 + 64]), xa1);
        xb0 = mfma_(as_bf(ax1), as_bf(ldsW[lb1]),      xb0);
        xb1 = mfma_(as_bf(ax1), as_bf(ldsW[lb1 + 64]), xb1);
      }
    } else {
      const float* xF = inp + ((size_t)arow * Tt + t) * Dd + koff8 * 8;
      #pragma unroll 4
      for (int kc = 0; kc < 32; ++kc) {
        const float* xs = xF + kc * 32;
        uint4 axu;
        axu.x = pk2(xs[0], xs[1]); axu.y = pk2(xs[2], xs[3]);
        axu.z = pk2(xs[4], xs[5]); axu.w = pk2(xs[6], xs[7]);
        const int lb = kc * 256 + l;
        xa0 = mfma_(as_bf(axu), as_bf(ldsW[lb]),      xa0);
        xa1 = mfma_(as_bf(axu), as_bf(ldsW[lb + 64]), xa1);
      }
    }

    // ---- check preloaded flags; spin-reload only on genuine skew
    {
      int ok = ((int)fc0 >= t) && ((int)(fc0 >> 32) >= t) &&
               ((int)fc1 >= t) && ((int)(fc1 >> 32) >= t) &&
               ((int)fc2 >= t) && ((int)(fc2 >> 32) >= t) &&
               ((int)fc3 >= t) && ((int)(fc3 >> 32) >= t);
      while (!__all(ok)) {
        fc0 = aload(&fq[l]);
        fc1 = aload(&fq[l + 64]);
        fc2 = aload(&fq[l + 128]);
        fc3 = aload(&fq[l + 192]);
        ok = ((int)fc0 >= t) && ((int)(fc0 >> 32) >= t) &&
             ((int)fc1 >= t) && ((int)(fc1 >> 32) >= t) &&
             ((int)fc2 >= t) && ((int)(fc2 >> 32) >= t) &&
             ((int)fc3 >= t) && ((int)(fc3 >> 32) >= t);
      }
    }

    // ---- h-part, sweep rotated by gs to spread LLC contention
    const u64* hA = hQ + (size_t)cur * 32768;
    #pragma unroll
    for (int pp = 0; pp < 16; ++pp) {
      const int p = (pp + rot) & 15;
      const int kc = 2 * p;
      const int hi0 = (kc * 4 + koff8) * 256 + arow * 2;
      const int hi1 = ((kc + 1) * 4 + koff8) * 256 + arow * 2;
      union { u64 q[2]; uint4 p4; } h0u, h1u;
      h0u.q[0] = aload(&hA[hi0]); h0u.q[1] = aload(&hA[hi0 + 1]);
      h1u.q[0] = aload(&hA[hi1]); h1u.q[1] = aload(&hA[hi1 + 1]);
      const int lb0 = kc * 256 + l, lb1 = (kc + 1) * 256 + l;
      xa0 = mfma_(as_bf(h0u.p4), as_bf(ldsW[lb0 + 128]), xa0);
      xa1 = mfma_(as_bf(h0u.p4), as_bf(ldsW[lb0 + 192]), xa1);
      xb0 = mfma_(as_bf(h1u.p4), as_bf(ldsW[lb1 + 128]), xb0);
      xb1 = mfma_(as_bf(h1u.p4), as_bf(ldsW[lb1 + 192]), xb1);
    }
    f32x4 acc0 = xa0 + xb0;
    f32x4 acc1 = xa1 + xb1;

    // ---- pointwise (acc0: i|f, acc1: g|o split at col 8)
    float fo0[4], fo1[4];
    #pragma unroll
    for (int j = 0; j < 4; ++j) {
      fo0[j] = __shfl_xor(acc0[j], 8);
      fo1[j] = __shfl_xor(acc1[j], 8);
    }
    unsigned int bfu0 = 0, bfu1 = 0, bfu2 = 0, bfu3 = 0;
    if (c < 8) {
      float hnv[4];
      #pragma unroll
      for (int j = 0; j < 4; ++j) {
        float iv = sigm(acc0[j]);
        float fv = sigm(fo0[j]);
        float gv = tanh_s(acc1[j]);
        float ov = sigm(fo1[j]);
        float cn = fv * creg[j] + iv * gv;
        float hn = ov * tanh_s(cn);
        creg[j] = cn;
        hnv[j] = hn;
        if (t == Tt - 1) {
          size_t off = (size_t)(crow + j) * Dd + dim;
          __hip_atomic_store(&out_h[off], hn, __ATOMIC_RELAXED, __HIP_MEMORY_SCOPE_AGENT);
          __hip_atomic_store(&out_c[off], cn, __ATOMIC_RELAXED, __HIP_MEMORY_SCOPE_AGENT);
        }
      }
      bfu0 = f2bf(hnv[0]); bfu1 = f2bf(hnv[1]);
      bfu2 = f2bf(hnv[2]); bfu3 = f2bf(hnv[3]);
    }

    // ---- in-wave transpose: lane r<16 gathers row (rowbase+r), dims 0..7
    unsigned int w0 = 0, w1 = 0, w2 = 0, w3 = 0;
    #pragma unroll
    for (int j = 0; j < 4; ++j) {
      unsigned int src = (j == 0) ? bfu0 : (j == 1) ? bfu1 : (j == 2) ? bfu2 : bfu3;
      unsigned int lo0 = __shfl((int)src, shbase + 0);
      unsigned int hi0g = __shfl((int)src, shbase + 1);
      unsigned int lo1 = __shfl((int)src, shbase + 2);
      unsigned int hi1g = __shfl((int)src, shbase + 3);
      unsigned int lo2 = __shfl((int)src, shbase + 4);
      unsigned int hi2g = __shfl((int)src, shbase + 5);
      unsigned int lo3 = __shfl((int)src, shbase + 6);
      unsigned int hi3g = __shfl((int)src, shbase + 7);
      bool mine = ((l & 3) == j);
      if (mine) {
        w0 = lo0 | (hi0g << 16);
        w1 = lo1 | (hi1g << 16);
        w2 = lo2 | (hi2g << 16);
        w3 = lo3 | (hi3g << 16);
      }
    }
    if (l < 16) {
      u32x4 val = {w0, w1, w2, w3};
      unsigned short* hw = hbuf + (size_t)(cur ^ 1) * 131072
                           + (size_t)gs * 1024 + (size_t)(rowbase + l) * 8;
      asm volatile("global_store_dwordx4 %0, %1, off sc0 sc1"
                   :: "v"(hw), "v"(val) : "memory");
    }
    asm volatile("s_waitcnt vmcnt(0)" ::: "memory");  // h globally visible
    if (l == 0)
      __hip_atomic_store(myflag, t + 1, __ATOMIC_RELAXED, __HIP_MEMORY_SCOPE_AGENT);
  }

  // ---------- fc head: yhat[b] = sigmoid(hx[b,:] . fc_w + fc_b)
  if (wg < Bb) {
    // wait for BOTH halves to finish (bh-split barrier doesn't cover this)
    {
      const u64* fa = (const u64*)flags;   // 512 u64 total
      int ok;
      do {
        ok = 1;
        #pragma unroll
        for (int r = 0; r < 8; ++r) {
          u64 v = aload(&fa[l + r * 64]);
          ok &= ((int)v >= Tt) && ((int)(v >> 32) >= Tt);
        }
      } while (!__all(ok));
    }
    const u64* hr = (const u64*)(out_h + (size_t)wg * Dd);
    float s = 0.f;
    for (int k = tid; k < Dd / 2; k += NTHR) {
      u64 v = aload(&hr[k]);
      union { u64 u; float f[2]; } q; q.u = v;
      s += q.f[0] * fc_w[2 * k] + q.f[1] * fc_w[2 * k + 1];
    }
    #pragma unroll
    for (int off = 32; off > 0; off >>= 1) s += __shfl_down(s, off);
    if (l == 0) red[w] = s;
    __syncthreads();
    if (tid == 0) {
      float tot = red[0] + red[1] + red[2] + red[3] + fc_b[0];
      out_y[wg] = sigm(tot);
    }
  }
}

extern "C" void kernel_launch(void* const* d_in, const int* in_sizes, int n_in,
                              void* d_out, int out_size, void* d_ws, size_t ws_size,
                              hipStream_t stream) {
  (void)in_sizes; (void)n_in; (void)out_size;
  const float* inp  = (const float*)d_in[0];
  const float* h0   = (const float*)d_in[1];
  const float* c0   = (const float*)d_in[2];
  const float* W_ih = (const float*)d_in[3];
  const float* W_hh = (const float*)d_in[4];
  const float* b_ih = (const float*)d_in[5];
  const float* b_hh = (const float*)d_in[6];
  const float* fc_w = (const float*)d_in[7];
  const float* fc_b = (const float*)d_in[8];
  float* out = (float*)d_out;

  // ws layout: flags 4KB (1024 ints) | hbuf 2x256KB bf16 double buffer | xbf 64MB
  size_t fbytes = 4096;
  size_t hbytes = (size_t)2 * Bb * Dd * 2;
  size_t xbytes = (size_t)Tt * Bb * Dd * 2;
  int* flags = (int*)d_ws;
  unsigned short* hbuf = (unsigned short*)((char*)d_ws + fbytes);
  unsigned short* xbf  = (unsigned short*)((char*)d_ws + fbytes + hbytes);
  int use_xbf = (ws_size >= fbytes + hbytes + xbytes) ? 1 : 0;

  (void)hipFuncSetAttribute((const void*)lstm_kernel,
                            hipFuncAttributeMaxDynamicSharedMemorySize, 131072);

  void* kargs[] = {(void*)&inp, (void*)&h0, (void*)&c0, (void*)&W_ih, (void*)&W_hh,
                   (void*)&b_ih, (void*)&b_hh, (void*)&fc_w, (void*)&fc_b,
                   (void*)&out, (void*)&flags, (void*)&hbuf, (void*)&xbf, (void*)&use_xbf};
  (void)hipLaunchCooperativeKernel((void*)lstm_kernel, dim3(NWG), dim3(NTHR),
                                   kargs, 131072u, stream);
}

// Round 7
// 2878.278 us; speedup vs baseline: 1.1683x; 1.1683x over previous
//
#include <hip/hip_runtime.h>
#include <hip/hip_cooperative_groups.h>

namespace cg = cooperative_groups;

#define Dd 1024
#define Bb 128
#define Tt 256
#define NWG 256
#define NTHR 256

typedef short bf16x8 __attribute__((ext_vector_type(8)));
typedef float f32x4 __attribute__((ext_vector_type(4)));
typedef unsigned int u32x4 __attribute__((ext_vector_type(4)));
typedef unsigned long long u64;

static __device__ __forceinline__ unsigned short f2bf(float x) {
  unsigned int u = __float_as_uint(x);
  u += 0x7fffu + ((u >> 16) & 1u);   // round-to-nearest-even
  return (unsigned short)(u >> 16);
}
static __device__ __forceinline__ unsigned int pk2(float a, float b) {
  return (unsigned int)f2bf(a) | ((unsigned int)f2bf(b) << 16);
}
static __device__ __forceinline__ bf16x8 as_bf(uint4 u) {
  union { uint4 u; bf16x8 v; } x; x.u = u; return x.v;
}
static __device__ __forceinline__ f32x4 mfma_(bf16x8 a, bf16x8 b, f32x4 c) {
  return __builtin_amdgcn_mfma_f32_16x16x32_bf16(a, b, c, 0, 0, 0);
}
static __device__ __forceinline__ float sigm(float x) { return 1.f / (1.f + __expf(-x)); }
static __device__ __forceinline__ float tanh_s(float x) { return 1.f - 2.f / (__expf(2.f * x) + 1.f); }
static __device__ __forceinline__ u64 aload(const u64* p) {
  return __hip_atomic_load(p, __ATOMIC_RELAXED, __HIP_MEMORY_SCOPE_AGENT);
}

// 256 WGs x 256 thr. WG = (batch-half bh, hidden-slice gs of 8 dims).
// LDS: W_ih+W_hh slices packed as MFMA B-fragments (128 KB, resident).
// RING=1: h flows through a 257-slot ring (one fresh 256KB slot per step);
//   producers write-through (sc0 sc1), consumers use NORMAL cached loads
//   (slot addresses are single-writer, read-after-flag, first-touch in L2).
// RING=0: R4-style 2-slot double buffer with coherent-point atomic loads.
// Only wave 0 polls global flags; waves 1-3 spin on an LDS sentinel.
template<int RING>
__global__ void __launch_bounds__(NTHR, 1) lstm_kernel(
    const float* __restrict__ inp, const float* __restrict__ h0,
    const float* __restrict__ c0, const float* __restrict__ W_ih,
    const float* __restrict__ W_hh, const float* __restrict__ b_ih,
    const float* __restrict__ b_hh, const float* __restrict__ fc_w,
    const float* __restrict__ fc_b, float* __restrict__ out,
    int* __restrict__ flags, unsigned short* __restrict__ hbuf,
    unsigned short* __restrict__ xbf, int use_xbf)
{
  extern __shared__ uint4 ldsW[];   // 8192 fragments = 128 KB
  __shared__ float red[4];
  __shared__ int sent;

  const int tid = threadIdx.x;
  const int wg  = blockIdx.x;
  const int gid = wg * NTHR + tid;
  cg::grid_group grid = cg::this_grid();

  const int gs = wg >> 1;
  const int bh = wg & 1;

  // ---------- flag init: 4 per WG (one per wave), layout [bh][gs][wave]
  if (tid < 4)
    __hip_atomic_store(&flags[bh * 512 + gs * 4 + tid], 0,
                       __ATOMIC_RELAXED, __HIP_MEMORY_SCOPE_AGENT);
  if (tid == 0) sent = -1;

  // ---------- Phase A: inp [B,T,D] f32 -> xbf [T,B,D] bf16 ; h0 -> slot 0
  if (use_xbf) {
    for (int i = gid; i < Tt * Bb * (Dd / 8); i += NWG * NTHR) {
      int d8 = i & 127, b = (i >> 7) & 127, t = i >> 14;
      const float* s = inp + ((size_t)b * Tt + t) * Dd + d8 * 8;
      uint4 p;
      p.x = pk2(s[0], s[1]); p.y = pk2(s[2], s[3]);
      p.z = pk2(s[4], s[5]); p.w = pk2(s[6], s[7]);
      *(uint4*)(xbf + (size_t)i * 8) = p;
    }
  }
  // h0 [b][d] f32 -> slot0 [d>>3][b][d&7] bf16
  uint4* hb4w = (uint4*)hbuf;
  for (int i = gid; i < 128 * 128; i += NWG * NTHR) {
    int row = i & 127, gsl = i >> 7;
    const float* s = h0 + (size_t)row * Dd + gsl * 8;
    uint4 p;
    p.x = pk2(s[0], s[1]); p.y = pk2(s[2], s[3]);
    p.z = pk2(s[4], s[5]); p.w = pk2(s[6], s[7]);
    hb4w[gsl * 128 + row] = p;
  }

  // ---------- Phase B: pack W slices into LDS (bf16, fragment order)
  for (int i = tid; i < 8192; i += NTHR) {
    int l2 = i & 63, mmct = (i >> 6) & 3, kc = i >> 8;
    int cc = l2 & 15, ct = mmct & 1;
    int row = (((ct << 1) | (cc >> 3)) << 10) | (gs << 3) | (cc & 7);
    int k = kc * 32 + ((l2 >> 4) << 3);
    const float* s = ((mmct & 2) ? W_hh : W_ih) + (size_t)row * Dd + k;
    uint4 p;
    p.x = pk2(s[0], s[1]); p.y = pk2(s[2], s[3]);
    p.z = pk2(s[4], s[5]); p.w = pk2(s[6], s[7]);
    ldsW[i] = p;
  }

  // ---------- per-thread setup
  const int w = tid >> 6, l = tid & 63;
  const int c = l & 15;
  const int rowbase = bh * 64 + w * 16;
  const int arow = rowbase + c;                 // A-fragment batch row
  const int koff8 = l >> 4;                     // k sub-chunk (0..3) within 32
  const int r0 = ((c >> 3) << 10) | (gs << 3) | (c & 7);        // i/f row
  const int r1 = ((2 + (c >> 3)) << 10) | (gs << 3) | (c & 7);  // g/o row
  const float bias0 = b_ih[r0] + b_hh[r0];
  const float bias1 = b_ih[r1] + b_hh[r1];
  const int dim = (gs << 3) | (c & 7);
  const int crow = rowbase + (koff8 << 2);      // C/D fragment row base
  float creg[4];
  #pragma unroll
  for (int j = 0; j < 4; ++j) creg[j] = c0[(size_t)(crow + j) * Dd + dim];

  float* out_y = out;
  float* out_h = out + Bb;
  float* out_c = out + Bb + (size_t)Bb * Dd;

  int* myflag = &flags[bh * 512 + gs * 4 + w];
  const u64* fq = (const u64*)(flags + bh * 512);  // 256 u64 = this half
  const int shbase = ((l & 15) >> 2) * 16;         // shfl source base

  grid.sync();   // one-time: publish flags reset, xbf, slot0 (release+acquire)

  // ---------- sequential scan (no syncthreads, no fences)
  for (int t = 0; t < Tt; ++t) {
    const int rslot = RING ? t : (t & 1);
    const int wslot = RING ? (t + 1) : ((t + 1) & 1);

    // ---- x-part: no dependency on h(t)
    f32x4 xa0 = {bias0, bias0, bias0, bias0};
    f32x4 xa1 = {bias1, bias1, bias1, bias1};
    f32x4 xb0 = {0.f, 0.f, 0.f, 0.f};
    f32x4 xb1 = {0.f, 0.f, 0.f, 0.f};

    if (use_xbf) {
      const uint4* xA = (const uint4*)(xbf + ((size_t)t * Bb + arow) * Dd + koff8 * 8);
      #pragma unroll
      for (int kc = 0; kc < 32; kc += 2) {
        uint4 ax0 = xA[kc * 4];
        uint4 ax1 = xA[(kc + 1) * 4];
        const int lb0 = kc * 256 + l, lb1 = (kc + 1) * 256 + l;
        xa0 = mfma_(as_bf(ax0), as_bf(ldsW[lb0]),      xa0);
        xa1 = mfma_(as_bf(ax0), as_bf(ldsW[lb0 + 64]), xa1);
        xb0 = mfma_(as_bf(ax1), as_bf(ldsW[lb1]),      xb0);
        xb1 = mfma_(as_bf(ax1), as_bf(ldsW[lb1 + 64]), xb1);
      }
    } else {
      const float* xF = inp + ((size_t)arow * Tt + t) * Dd + koff8 * 8;
      #pragma unroll 4
      for (int kc = 0; kc < 32; ++kc) {
        const float* xs = xF + kc * 32;
        uint4 axu;
        axu.x = pk2(xs[0], xs[1]); axu.y = pk2(xs[2], xs[3]);
        axu.z = pk2(xs[4], xs[5]); axu.w = pk2(xs[6], xs[7]);
        const int lb = kc * 256 + l;
        xa0 = mfma_(as_bf(axu), as_bf(ldsW[lb]),      xa0);
        xa1 = mfma_(as_bf(axu), as_bf(ldsW[lb + 64]), xa1);
      }
    }

    // ---- wait for h(t): wave 0 polls global flags, others spin LDS sentinel
    if (w == 0) {
      int ok;
      do {
        u64 a = aload(&fq[l]);
        u64 b = aload(&fq[l + 64]);
        u64 c2 = aload(&fq[l + 128]);
        u64 d2 = aload(&fq[l + 192]);
        ok = ((int)a >= t) && ((int)(a >> 32) >= t) &&
             ((int)b >= t) && ((int)(b >> 32) >= t) &&
             ((int)c2 >= t) && ((int)(c2 >> 32) >= t) &&
             ((int)d2 >= t) && ((int)(d2 >> 32) >= t);
      } while (!__all(ok));
      __hip_atomic_store(&sent, t, __ATOMIC_RELEASE, __HIP_MEMORY_SCOPE_WORKGROUP);
    } else {
      while (__hip_atomic_load(&sent, __ATOMIC_ACQUIRE, __HIP_MEMORY_SCOPE_WORKGROUP) < t) {}
    }
    asm volatile("" ::: "memory");   // compiler fence: no h-load hoisting

    // ---- h-part
    if constexpr (RING) {
      const uint4* hA4 = (const uint4*)(hbuf + (size_t)rslot * 131072);
      #pragma unroll
      for (int kc = 0; kc < 32; kc += 2) {
        uint4 h0u = hA4[(kc * 4 + koff8) * 128 + arow];
        uint4 h1u = hA4[((kc + 1) * 4 + koff8) * 128 + arow];
        const int lb0 = kc * 256 + l, lb1 = (kc + 1) * 256 + l;
        xa0 = mfma_(as_bf(h0u), as_bf(ldsW[lb0 + 128]), xa0);
        xa1 = mfma_(as_bf(h0u), as_bf(ldsW[lb0 + 192]), xa1);
        xb0 = mfma_(as_bf(h1u), as_bf(ldsW[lb1 + 128]), xb0);
        xb1 = mfma_(as_bf(h1u), as_bf(ldsW[lb1 + 192]), xb1);
      }
    } else {
      const u64* hA = (const u64*)hbuf + (size_t)rslot * 32768;
      #pragma unroll
      for (int kc = 0; kc < 32; kc += 2) {
        const int hi0 = (kc * 4 + koff8) * 256 + arow * 2;
        const int hi1 = ((kc + 1) * 4 + koff8) * 256 + arow * 2;
        union { u64 q[2]; uint4 p4; } h0u, h1u;
        h0u.q[0] = aload(&hA[hi0]); h0u.q[1] = aload(&hA[hi0 + 1]);
        h1u.q[0] = aload(&hA[hi1]); h1u.q[1] = aload(&hA[hi1 + 1]);
        const int lb0 = kc * 256 + l, lb1 = (kc + 1) * 256 + l;
        xa0 = mfma_(as_bf(h0u.p4), as_bf(ldsW[lb0 + 128]), xa0);
        xa1 = mfma_(as_bf(h0u.p4), as_bf(ldsW[lb0 + 192]), xa1);
        xb0 = mfma_(as_bf(h1u.p4), as_bf(ldsW[lb1 + 128]), xb0);
        xb1 = mfma_(as_bf(h1u.p4), as_bf(ldsW[lb1 + 192]), xb1);
      }
    }
    f32x4 acc0 = xa0 + xb0;
    f32x4 acc1 = xa1 + xb1;

    // ---- pointwise (acc0: i|f, acc1: g|o split at col 8)
    float fo0[4], fo1[4];
    #pragma unroll
    for (int j = 0; j < 4; ++j) {
      fo0[j] = __shfl_xor(acc0[j], 8);
      fo1[j] = __shfl_xor(acc1[j], 8);
    }
    unsigned int bfu0 = 0, bfu1 = 0, bfu2 = 0, bfu3 = 0;
    if (c < 8) {
      float hnv[4];
      #pragma unroll
      for (int j = 0; j < 4; ++j) {
        float iv = sigm(acc0[j]);
        float fv = sigm(fo0[j]);
        float gv = tanh_s(acc1[j]);
        float ov = sigm(fo1[j]);
        float cn = fv * creg[j] + iv * gv;
        float hn = ov * tanh_s(cn);
        creg[j] = cn;
        hnv[j] = hn;
        if (t == Tt - 1) {
          size_t off = (size_t)(crow + j) * Dd + dim;
          __hip_atomic_store(&out_h[off], hn, __ATOMIC_RELAXED, __HIP_MEMORY_SCOPE_AGENT);
          __hip_atomic_store(&out_c[off], cn, __ATOMIC_RELAXED, __HIP_MEMORY_SCOPE_AGENT);
        }
      }
      bfu0 = f2bf(hnv[0]); bfu1 = f2bf(hnv[1]);
      bfu2 = f2bf(hnv[2]); bfu3 = f2bf(hnv[3]);
    }

    // ---- in-wave transpose: lane r<16 gathers row (rowbase+r), dims 0..7
    unsigned int w0 = 0, w1 = 0, w2 = 0, w3 = 0;
    #pragma unroll
    for (int j = 0; j < 4; ++j) {
      unsigned int src = (j == 0) ? bfu0 : (j == 1) ? bfu1 : (j == 2) ? bfu2 : bfu3;
      unsigned int lo0 = __shfl((int)src, shbase + 0);
      unsigned int hi0g = __shfl((int)src, shbase + 1);
      unsigned int lo1 = __shfl((int)src, shbase + 2);
      unsigned int hi1g = __shfl((int)src, shbase + 3);
      unsigned int lo2 = __shfl((int)src, shbase + 4);
      unsigned int hi2g = __shfl((int)src, shbase + 5);
      unsigned int lo3 = __shfl((int)src, shbase + 6);
      unsigned int hi3g = __shfl((int)src, shbase + 7);
      bool mine = ((l & 3) == j);
      if (mine) {
        w0 = lo0 | (hi0g << 16);
        w1 = lo1 | (hi1g << 16);
        w2 = lo2 | (hi2g << 16);
        w3 = lo3 | (hi3g << 16);
      }
    }
    if (l < 16) {
      u32x4 val = {w0, w1, w2, w3};
      unsigned short* hw = hbuf + (size_t)wslot * 131072
                           + (size_t)gs * 1024 + (size_t)(rowbase + l) * 8;
      asm volatile("global_store_dwordx4 %0, %1, off sc0 sc1"
                   :: "v"(hw), "v"(val) : "memory");
    }
    asm volatile("s_waitcnt vmcnt(0)" ::: "memory");  // h globally visible
    if (l == 0)
      __hip_atomic_store(myflag, t + 1, __ATOMIC_RELAXED, __HIP_MEMORY_SCOPE_AGENT);
  }

  // ---------- fc head: yhat[b] = sigmoid(hx[b,:] . fc_w + fc_b)
  if (wg < Bb) {
    // wait for BOTH halves to finish (bh-split barrier doesn't cover this)
    {
      const u64* fa = (const u64*)flags;   // 512 u64 total
      int ok;
      do {
        ok = 1;
        #pragma unroll
        for (int r = 0; r < 8; ++r) {
          u64 v = aload(&fa[l + r * 64]);
          ok &= ((int)v >= Tt) && ((int)(v >> 32) >= Tt);
        }
      } while (!__all(ok));
    }
    const u64* hr = (const u64*)(out_h + (size_t)wg * Dd);
    float s = 0.f;
    for (int k = tid; k < Dd / 2; k += NTHR) {
      u64 v = aload(&hr[k]);
      union { u64 u; float f[2]; } q; q.u = v;
      s += q.f[0] * fc_w[2 * k] + q.f[1] * fc_w[2 * k + 1];
    }
    #pragma unroll
    for (int off = 32; off > 0; off >>= 1) s += __shfl_down(s, off);
    if (l == 0) red[w] = s;
    __syncthreads();
    if (tid == 0) {
      float tot = red[0] + red[1] + red[2] + red[3] + fc_b[0];
      out_y[wg] = sigm(tot);
    }
  }
}

extern "C" void kernel_launch(void* const* d_in, const int* in_sizes, int n_in,
                              void* d_out, int out_size, void* d_ws, size_t ws_size,
                              hipStream_t stream) {
  (void)in_sizes; (void)n_in; (void)out_size;
  const float* inp  = (const float*)d_in[0];
  const float* h0   = (const float*)d_in[1];
  const float* c0   = (const float*)d_in[2];
  const float* W_ih = (const float*)d_in[3];
  const float* W_hh = (const float*)d_in[4];
  const float* b_ih = (const float*)d_in[5];
  const float* b_hh = (const float*)d_in[6];
  const float* fc_w = (const float*)d_in[7];
  const float* fc_b = (const float*)d_in[8];
  float* out = (float*)d_out;

  const size_t fbytes = 4096;
  const size_t slot   = (size_t)Bb * Dd * 2;           // 256 KB
  const size_t ring1  = (size_t)(Tt + 1) * slot;       // 67.4 MB
  const size_t ring0  = 2 * slot;                      // 512 KB
  const size_t xbytes = (size_t)Tt * Bb * Dd * 2;      // 64 MB

  int ring, use_xbf;
  size_t rbytes;
  if (ws_size >= fbytes + ring1 + xbytes)      { ring = 1; use_xbf = 1; rbytes = ring1; }
  else if (ws_size >= fbytes + ring1)          { ring = 1; use_xbf = 0; rbytes = ring1; }
  else if (ws_size >= fbytes + ring0 + xbytes) { ring = 0; use_xbf = 1; rbytes = ring0; }
  else                                         { ring = 0; use_xbf = 0; rbytes = ring0; }

  int* flags = (int*)d_ws;
  unsigned short* hbuf = (unsigned short*)((char*)d_ws + fbytes);
  unsigned short* xbf  = (unsigned short*)((char*)d_ws + fbytes + rbytes);

  void* kfn = ring ? (void*)lstm_kernel<1> : (void*)lstm_kernel<0>;
  (void)hipFuncSetAttribute((const void*)kfn,
                            hipFuncAttributeMaxDynamicSharedMemorySize, 131072);

  void* kargs[] = {(void*)&inp, (void*)&h0, (void*)&c0, (void*)&W_ih, (void*)&W_hh,
                   (void*)&b_ih, (void*)&b_hh, (void*)&fc_w, (void*)&fc_b,
                   (void*)&out, (void*)&flags, (void*)&hbuf, (void*)&xbf, (void*)&use_xbf};
  (void)hipLaunchCooperativeKernel(kfn, dim3(NWG), dim3(NTHR),
                                   kargs, 131072u, stream);
}